// Round 4
// baseline (141.057 us; speedup 1.0000x reference)
//
#include <hip/hip_runtime.h>

#define CLS 512
#define NROWS 32768
#define WPB 4
#define NBLOCKS 2048   // 2048 blocks * 4 waves * 4 rows/wave = 32768 rows, one shot

__global__ __launch_bounds__(256) void lr_fused_kernel(
    const float* __restrict__ out, const int* __restrict__ tgt,
    float* __restrict__ partial, unsigned int* __restrict__ counter,
    float* __restrict__ loss) {
  const int lane = threadIdx.x & 63;
  const int wid  = threadIdx.x >> 6;
  const int gw   = blockIdx.x * WPB + wid;          // 0..8191
  const size_t base = (size_t)gw * 4 * CLS;         // 4 consecutive rows per wave

  const float4* po = reinterpret_cast<const float4*>(out + base);
  const int4*   pt = reinterpret_cast<const int4*>(tgt + base);

  // 16 full-wave contiguous 1KB loads, all hoisted (one latency exposure).
  float4 o[8];
  int4   t[8];
#pragma unroll
  for (int r = 0; r < 4; ++r) {
    o[2 * r]     = po[r * 128 + lane];
    o[2 * r + 1] = po[r * 128 + 64 + lane];
    t[2 * r]     = pt[r * 128 + lane];
    t[2 * r + 1] = pt[r * 128 + 64 + lane];
  }

  float acc = 0.0f;
#pragma unroll
  for (int r = 0; r < 4; ++r) {
    float s_neg = 0.0f, s_pos = 0.0f, np = 0.0f;
#pragma unroll
    for (int k = 0; k < 2; ++k) {
      float4 ov = o[2 * r + k];
      int4   tv = t[2 * r + k];
      float vx[4] = {ov.x, ov.y, ov.z, ov.w};
      int   mx[4] = {tv.x, tv.y, tv.z, tv.w};
#pragma unroll
      for (int j = 0; j < 4; ++j) {
        float e = __expf(mx[j] ? -vx[j] : vx[j]);
        s_pos += mx[j] ? e : 0.0f;
        s_neg += mx[j] ? 0.0f : e;
        np    += mx[j] ? 1.0f : 0.0f;
      }
    }
#pragma unroll
    for (int m = 1; m < 64; m <<= 1) {
      s_neg += __shfl_xor(s_neg, m);
      s_pos += __shfl_xor(s_pos, m);
      np    += __shfl_xor(np, m);
    }
    float num = np * ((float)CLS - np);
    if (num == 0.0f) num = (float)CLS;
    acc += s_neg * s_pos / num;     // same in every lane
  }

  __shared__ float sacc[WPB];
  __shared__ bool  is_last;
  if (lane == 0) sacc[wid] = acc;
  __syncthreads();

  if (threadIdx.x == 0) {
    float v = sacc[0] + sacc[1] + sacc[2] + sacc[3];
    // release-store partial at agent scope, then acq_rel ticket: the RMW chain
    // makes all partials visible to whichever block draws the last ticket
    // (coherence-point ops, safe across non-coherent per-XCD L2s).
    __hip_atomic_store(&partial[blockIdx.x], v, __ATOMIC_RELEASE,
                       __HIP_MEMORY_SCOPE_AGENT);
    unsigned tk = __hip_atomic_fetch_add(counter, 1u, __ATOMIC_ACQ_REL,
                                         __HIP_MEMORY_SCOPE_AGENT);
    is_last = (tk == NBLOCKS - 1);
  }
  __syncthreads();      // is_last is block-uniform

  if (is_last) {
    float s = 0.0f;
#pragma unroll
    for (int i = threadIdx.x; i < NBLOCKS; i += 256)
      s += __hip_atomic_load(&partial[i], __ATOMIC_RELAXED,
                             __HIP_MEMORY_SCOPE_AGENT);
#pragma unroll
    for (int m = 1; m < 64; m <<= 1) s += __shfl_xor(s, m);
    __shared__ float w[4];
    if (lane == 0) w[wid] = s;
    __syncthreads();
    if (threadIdx.x == 0) loss[0] = w[0] + w[1] + w[2] + w[3];
  }
}

extern "C" void kernel_launch(void* const* d_in, const int* in_sizes, int n_in,
                              void* d_out, int out_size, void* d_ws, size_t ws_size,
                              hipStream_t stream) {
  const float* output = (const float*)d_in[0];
  const int*   target = (const int*)d_in[1];
  unsigned int* counter = (unsigned int*)d_ws;                  // 4 B, zeroed below
  float*        partial = (float*)((char*)d_ws + 256);          // NBLOCKS floats
  float*        loss    = (float*)d_out;

  hipMemsetAsync(d_ws, 0, 256, stream);   // zero the ticket counter (graph-legal)
  lr_fused_kernel<<<NBLOCKS, 256, 0, stream>>>(output, target, partial, counter, loss);
}

// Round 5
// 27.590 us; speedup vs baseline: 5.1127x; 5.1127x over previous
//
#include <hip/hip_runtime.h>

#define CLS 512
#define NROWS 32768
#define WPB 4
#define NBLOCKS 2048   // 2048 blocks * 4 waves * 4 rows/wave = 32768 rows, one shot

// f32 add with DPP-shifted operand (VALU pipe, no DS/lgkmcnt).
template <int CTRL, int ROWM>
__device__ __forceinline__ float dpp_add(float x) {
  int s = __builtin_amdgcn_update_dpp(0, __float_as_int(x), CTRL, ROWM, 0xf, true);
  return x + __int_as_float(s);
}

// Standard wave64 sum: after this, lane 63 holds the full 64-lane sum.
__device__ __forceinline__ float wave_sum_dpp(float x) {
  x = dpp_add<0x111, 0xf>(x);  // row_shr:1
  x = dpp_add<0x112, 0xf>(x);  // row_shr:2
  x = dpp_add<0x114, 0xf>(x);  // row_shr:4
  x = dpp_add<0x118, 0xf>(x);  // row_shr:8  -> lane15 of each 16-row = row sum
  x = dpp_add<0x142, 0xa>(x);  // row_bcast:15 into rows 1,3
  x = dpp_add<0x143, 0xc>(x);  // row_bcast:31 into rows 2,3 -> lane 63 = total
  return x;
}

__global__ __launch_bounds__(256) void lr_main_kernel(
    const float* __restrict__ out, const int* __restrict__ tgt,
    float* __restrict__ partial) {
  const int lane = threadIdx.x & 63;
  const int wid  = threadIdx.x >> 6;
  const int gw   = blockIdx.x * WPB + wid;          // 0..8191
  const size_t base = (size_t)gw * 4 * CLS;         // 4 consecutive rows per wave

  const float4* po = reinterpret_cast<const float4*>(out + base);
  const int4*   pt = reinterpret_cast<const int4*>(tgt + base);

  // 16 full-wave contiguous 1KB loads, all hoisted (one latency exposure).
  float4 o[8];
  int4   t[8];
#pragma unroll
  for (int r = 0; r < 4; ++r) {
    o[2 * r]     = po[r * 128 + lane];
    o[2 * r + 1] = po[r * 128 + 64 + lane];
    t[2 * r]     = pt[r * 128 + lane];
    t[2 * r + 1] = pt[r * 128 + 64 + lane];
  }

  float acc = 0.0f;   // only lane 63's value is meaningful
#pragma unroll
  for (int r = 0; r < 4; ++r) {
    float s_neg = 0.0f, s_pos = 0.0f, np = 0.0f;
#pragma unroll
    for (int k = 0; k < 2; ++k) {
      float4 ov = o[2 * r + k];
      int4   tv = t[2 * r + k];
      float vx[4] = {ov.x, ov.y, ov.z, ov.w};
      int   mx[4] = {tv.x, tv.y, tv.z, tv.w};
#pragma unroll
      for (int j = 0; j < 4; ++j) {
        float e = __expf(mx[j] ? -vx[j] : vx[j]);
        s_pos += mx[j] ? e : 0.0f;
        s_neg += mx[j] ? 0.0f : e;
        np    += mx[j] ? 1.0f : 0.0f;
      }
    }
    // VALU-pipe reductions; independent chains across rows/values give ILP.
    s_neg = wave_sum_dpp(s_neg);
    s_pos = wave_sum_dpp(s_pos);
    np    = wave_sum_dpp(np);

    float num = np * ((float)CLS - np);
    if (num == 0.0f) num = (float)CLS;
    acc += s_neg * s_pos / num;     // valid in lane 63
  }

  __shared__ float sacc[WPB];
  if (lane == 63) sacc[wid] = acc;
  __syncthreads();
  if (threadIdx.x == 0)
    partial[blockIdx.x] = sacc[0] + sacc[1] + sacc[2] + sacc[3];
}

__global__ __launch_bounds__(256) void lr_final_kernel(
    const float* __restrict__ partial, float* __restrict__ out) {
  const int lane = threadIdx.x & 63;
  const int wid  = threadIdx.x >> 6;

  float s = 0.0f;
#pragma unroll
  for (int i = threadIdx.x; i < NBLOCKS; i += 256) s += partial[i];

#pragma unroll
  for (int m = 1; m < 64; m <<= 1) s += __shfl_xor(s, m);

  __shared__ float w[4];
  if (lane == 0) w[wid] = s;
  __syncthreads();
  if (threadIdx.x == 0) out[0] = w[0] + w[1] + w[2] + w[3];
}

extern "C" void kernel_launch(void* const* d_in, const int* in_sizes, int n_in,
                              void* d_out, int out_size, void* d_ws, size_t ws_size,
                              hipStream_t stream) {
  const float* output = (const float*)d_in[0];
  const int*   target = (const int*)d_in[1];
  float* partial = (float*)d_ws;          // NBLOCKS floats = 8 KiB
  float* loss    = (float*)d_out;

  lr_main_kernel<<<NBLOCKS, 256, 0, stream>>>(output, target, partial);
  lr_final_kernel<<<1, 256, 0, stream>>>(partial, loss);
}